// Round 5
// baseline (181.042 us; speedup 1.0000x reference)
//
#include <hip/hip_runtime.h>
#include <hip/hip_bf16.h>

#define HH 128
#define WW 128
#define CC 64
#define TT 5
#define HW (HH*WW)
#define NI 10

typedef __attribute__((ext_vector_type(8))) short short8;
typedef __attribute__((ext_vector_type(4))) float f32x4;

__device__ __forceinline__ float bf2f(unsigned int bits16) {
  union { unsigned int u; float f; } v; v.u = bits16 << 16; return v.f;
}
__device__ __forceinline__ unsigned short f2bf(float f) {
  __hip_bfloat16 h = __float2bfloat16(f);
  return *reinterpret_cast<unsigned short*>(&h);
}

// ---- merged pack: blocks [0, NI*HH) transpose x; blocks [NI*HH, +144) pack weights.
// xb[n][h][w][ci] bf16; wb1[oc][kk][ic]; wb2[oc16][kk][ic] (rows 9..15 zero).
__global__ __launch_bounds__(256) void pack_k(const float* __restrict__ x,
    const float* __restrict__ w1, const float* __restrict__ w2,
    unsigned short* __restrict__ xb, unsigned short* __restrict__ wb1,
    unsigned short* __restrict__ wb2) {
  __shared__ unsigned short tb[128*68];
  const int tid = threadIdx.x;
  const int bx = blockIdx.x;
  if (bx >= NI*HH) {            // ---- weight part (144 blocks)
    int idx = (bx - NI*HH)*256 + tid;
    if (idx < 64*576) {
      int oc = idx / 576, rem = idx - oc*576, kk = rem >> 6, ic = rem & 63;
      wb1[idx] = f2bf(w1[(oc*64 + ic)*9 + kk]);
    }
    if (idx < 16*576) {
      int oc = idx / 576, rem = idx - oc*576, kk = rem >> 6, ic = rem & 63;
      wb2[idx] = (oc < 9) ? f2bf(w2[(oc*64 + ic)*9 + kk]) : (unsigned short)0;
    }
    return;
  }
  // ---- x part: one (n,h) row per block
  const int n = bx >> 7, h = bx & 127;
  const int bi = n / 5, ti = n - bi*5;
  const float* xp = x + ((size_t)bi*CC*TT + ti)*HW + (size_t)h*WW;
  for (int e = tid; e < 64*128; e += 256) {
    int ci = e >> 7, w = e & 127;
    tb[w*68 + ci] = f2bf(xp[(size_t)ci*TT*HW + w]);
  }
  __syncthreads();
  unsigned short* dst = xb + ((size_t)n*HW + (size_t)h*WW)*64;
  for (int e = tid; e < 2048; e += 256) {
    int w = e >> 4, c = e & 15;
    *(uint2*)(dst + w*64 + c*4) = *(const uint2*)(&tb[w*68 + c*4]);
  }
}

// ---- conv1 implicit-GEMM MFMA v3: 256 thr (4 waves), 16w x 8h tile, 32 oc.
// Wave owns 2 pixel-rows x 2 oc-groups -> acc 16 AGPR; LDS 23 KB -> 7 blocks/CU.
// grid (8,16,20): z = n*2 + ocg.
__global__ __launch_bounds__(256) void conv1_mfma(
    const unsigned short* __restrict__ xb, const unsigned short* __restrict__ wb1,
    const float* __restrict__ b1, unsigned short* __restrict__ yb) {
  __shared__ unsigned short xt[180*64];    // 10x18 halo x 64 ic = 23040 B
  const int tid = threadIdx.x;
  const int wave = tid >> 6, lane = tid & 63, q = lane >> 4, r = lane & 15;
  const int n = blockIdx.z >> 1, ocg = (blockIdx.z & 1) << 5;
  const int h0 = blockIdx.y << 3, w0 = blockIdx.x << 4;
  const unsigned short* xn = xb + (size_t)n*HW*64;

  for (int e = tid; e < 1440; e += 256) {           // 180 sp x 8 chunks, 16B each
    int sp = e >> 3, c = e & 7;
    int sr = sp / 18, sc = sp - sr*18;
    int gh = h0 + sr - 1, gw = w0 + sc - 1;
    uint4 v = make_uint4(0u,0u,0u,0u);
    if (gh >= 0 && gh < HH && gw >= 0 && gw < WW)
      v = *(const uint4*)(xn + ((size_t)(gh*WW + gw))*64 + (c << 3));
    *(uint4*)(&xt[sp*64 + ((c ^ (sp & 7)) << 3)]) = v;
  }
  __syncthreads();

  f32x4 zero4 = {0.f, 0.f, 0.f, 0.f};
  f32x4 acc[2][2];                                   // [row i][oc group g]
  #pragma unroll
  for (int i = 0; i < 2; ++i)
    #pragma unroll
    for (int g = 0; g < 2; ++g) acc[i][g] = zero4;

  #pragma unroll
  for (int kk = 0; kk < 9; ++kk) {
    const int dy = kk / 3, dx = kk - dy*3;
    #pragma unroll
    for (int half = 0; half < 2; ++half) {
      short8 a0 = *(const short8*)(wb1 + (size_t)(ocg +      r)*576 + kk*64 + half*32 + (q << 3));
      short8 a1 = *(const short8*)(wb1 + (size_t)(ocg + 16 + r)*576 + kk*64 + half*32 + (q << 3));
      #pragma unroll
      for (int i = 0; i < 2; ++i) {
        int sp = (wave*2 + i + dy)*18 + (r + dx);
        short8 b = *(const short8*)(&xt[sp*64 + ((((half << 2) | q) ^ (sp & 7)) << 3)]);
        acc[i][0] = __builtin_amdgcn_mfma_f32_16x16x32_bf16(a0, b, acc[i][0], 0, 0, 0);
        acc[i][1] = __builtin_amdgcn_mfma_f32_16x16x32_bf16(a1, b, acc[i][1], 0, 0, 0);
      }
    }
  }

  #pragma unroll
  for (int i = 0; i < 2; ++i) {
    int py = wave*2 + i;
    unsigned short* yp = yb + ((size_t)n*HW + (h0+py)*WW + (w0+r))*64;
    #pragma unroll
    for (int g = 0; g < 2; ++g) {
      int oc0 = ocg + g*16 + (q << 2);
      f32x4 bias = *(const f32x4*)(b1 + oc0);
      float v0 = acc[i][g][0] + bias[0]; v0 = (v0 >= 0.f) ? v0 : 0.2f*v0;
      float v1 = acc[i][g][1] + bias[1]; v1 = (v1 >= 0.f) ? v1 : 0.2f*v1;
      float v2 = acc[i][g][2] + bias[2]; v2 = (v2 >= 0.f) ? v2 : 0.2f*v2;
      float v3 = acc[i][g][3] + bias[3]; v3 = (v3 >= 0.f) ? v3 : 0.2f*v3;
      uint2 pk;
      pk.x = (unsigned int)f2bf(v0) | ((unsigned int)f2bf(v1) << 16);
      pk.y = (unsigned int)f2bf(v2) | ((unsigned int)f2bf(v3) << 16);
      *(uint2*)(yp + oc0) = pk;
    }
  }
}

// ---- conv2 MFMA v3: 256 thr, 16w x 8h tile, 16 oc (9 real). grid (8,16,10).
__global__ __launch_bounds__(256) void conv2_mfma(
    const unsigned short* __restrict__ yb, const unsigned short* __restrict__ wb2,
    const float* __restrict__ b2, float* __restrict__ ker0) {
  __shared__ unsigned short yt[180*64];
  const int tid = threadIdx.x;
  const int wave = tid >> 6, lane = tid & 63, q = lane >> 4, r = lane & 15;
  const int n = blockIdx.z;
  const int h0 = blockIdx.y << 3, w0 = blockIdx.x << 4;
  const unsigned short* yn = yb + (size_t)n*HW*64;

  for (int e = tid; e < 1440; e += 256) {
    int sp = e >> 3, c = e & 7;
    int sr = sp / 18, sc = sp - sr*18;
    int gh = h0 + sr - 1, gw = w0 + sc - 1;
    uint4 v = make_uint4(0u,0u,0u,0u);
    if (gh >= 0 && gh < HH && gw >= 0 && gw < WW)
      v = *(const uint4*)(yn + ((size_t)(gh*WW + gw))*64 + (c << 3));
    *(uint4*)(&yt[sp*64 + ((c ^ (sp & 7)) << 3)]) = v;
  }
  __syncthreads();

  f32x4 zero4 = {0.f, 0.f, 0.f, 0.f};
  f32x4 acc[2];
  #pragma unroll
  for (int i = 0; i < 2; ++i) acc[i] = zero4;

  #pragma unroll
  for (int kk = 0; kk < 9; ++kk) {
    const int dy = kk / 3, dx = kk - dy*3;
    #pragma unroll
    for (int half = 0; half < 2; ++half) {
      short8 a = *(const short8*)(wb2 + r*576 + kk*64 + half*32 + (q << 3));
      #pragma unroll
      for (int i = 0; i < 2; ++i) {
        int sp = (wave*2 + i + dy)*18 + (r + dx);
        short8 b = *(const short8*)(&yt[sp*64 + ((((half << 2) | q) ^ (sp & 7)) << 3)]);
        acc[i] = __builtin_amdgcn_mfma_f32_16x16x32_bf16(a, b, acc[i], 0, 0, 0);
      }
    }
  }

  #pragma unroll
  for (int i = 0; i < 2; ++i) {
    int py = wave*2 + i;
    #pragma unroll
    for (int t2 = 0; t2 < 4; ++t2) {
      int oc = (q << 2) + t2;
      if (oc < 9)
        ker0[((size_t)n*9 + oc)*HW + (h0+py)*WW + w0 + r] = acc[i][t2] + b2[oc];
    }
  }
}

// ---- dynamic filtering v3: 16x16 tile x 4 ci per block, grid (8,8,32).
// LDS 25.9 KB -> 6 blocks/CU (24 waves). One barrier.
__global__ __launch_bounds__(256) void dynf_k(
    const unsigned short* __restrict__ xb, const float* __restrict__ ker0,
    float* __restrict__ out) {
  __shared__ float xs[TT*324*4];           // 25920 B
  const int tw = threadIdx.x, th = threadIdx.y;
  const int tid = th*16 + tw;
  const int wz = blockIdx.z;
  const int bi = wz >> 4, ci0 = (wz & 15) << 2;
  const int h0 = blockIdx.y << 4, w0 = blockIdx.x << 4;
  const int pix = (h0+th)*WW + w0 + tw;

  float kv[45]; float s = 0.f;
  #pragma unroll
  for (int t5 = 0; t5 < TT; ++t5)
    #pragma unroll
    for (int kk = 0; kk < 9; ++kk) {
      float v = ker0[((size_t)(bi*TT + t5)*9 + kk)*HW + pix];
      kv[t5*9 + kk] = v; s += v;
    }
  const float m = (s - 1.f) * (1.f/45.f);   // mean - 1/45
  #pragma unroll
  for (int qq = 0; qq < 45; ++qq) kv[qq] -= m;

  for (int e = tid; e < TT*324; e += 256) {
    int t5 = e / 324, sp = e - t5*324;
    int rr = sp / 18, cc = sp - rr*18;
    int gh = min(max(h0 + rr - 1, 0), HH-1);
    int gw = min(max(w0 + cc - 1, 0), WW-1);
    uint2 raw = *(const uint2*)(xb + ((size_t)(bi*TT + t5)*HW + gh*WW + gw)*64 + ci0);
    f32x4 f;
    f[0] = bf2f(raw.x & 0xffffu);
    f[1] = bf2f(raw.x >> 16);
    f[2] = bf2f(raw.y & 0xffffu);
    f[3] = bf2f(raw.y >> 16);
    *(f32x4*)(&xs[e << 2]) = f;
  }
  __syncthreads();

  float a0 = 0.f, a1 = 0.f, a2 = 0.f, a3 = 0.f;
  #pragma unroll
  for (int t5 = 0; t5 < TT; ++t5)
    #pragma unroll
    for (int dy = 0; dy < 3; ++dy)
      #pragma unroll
      for (int dx = 0; dx < 3; ++dx) {
        f32x4 xv = *(const f32x4*)(&xs[(t5*324 + (th+dy)*18 + (tw+dx)) << 2]);
        float k = kv[t5*9 + dy*3 + dx];
        a0 = fmaf(xv[0], k, a0); a1 = fmaf(xv[1], k, a1);
        a2 = fmaf(xv[2], k, a2); a3 = fmaf(xv[3], k, a3);
      }
  float* op = out + ((size_t)(bi*CC + ci0))*HW + pix;
  op[0] = a0; op[HW] = a1; op[2*(size_t)HW] = a2; op[3*(size_t)HW] = a3;
}

extern "C" void kernel_launch(void* const* d_in, const int* in_sizes, int n_in,
                              void* d_out, int out_size, void* d_ws, size_t ws_size,
                              hipStream_t stream) {
  const float* x  = (const float*)d_in[0];
  const float* w1 = (const float*)d_in[1];
  const float* b1 = (const float*)d_in[2];
  const float* w2 = (const float*)d_in[3];
  const float* b2 = (const float*)d_in[4];
  float* out = (float*)d_out;

  unsigned short* xb  = (unsigned short*)d_ws;                 // 10*16384*64 bf16
  unsigned short* yb  = xb + (size_t)NI*HW*64;                 // same size
  float*          ker0 = (float*)(yb + (size_t)NI*HW*64);      // 10*9*16384 f32
  unsigned short* wb1 = (unsigned short*)(ker0 + (size_t)NI*9*HW);
  unsigned short* wb2 = wb1 + 64*576;

  pack_k    <<<NI*HH + 144, 256, 0, stream>>>(x, w1, w2, xb, wb1, wb2);
  conv1_mfma<<<dim3(8,16,2*NI), 256, 0, stream>>>(xb, wb1, b1, yb);
  conv2_mfma<<<dim3(8,16,NI), 256, 0, stream>>>(yb, wb2, b2, ker0);
  dynf_k    <<<dim3(8,8,32), dim3(16,16), 0, stream>>>(xb, ker0, out);
}

// Round 6
// 170.817 us; speedup vs baseline: 1.0599x; 1.0599x over previous
//
#include <hip/hip_runtime.h>
#include <hip/hip_bf16.h>

#define HH 128
#define WW 128
#define CC 64
#define TT 5
#define HW (HH*WW)
#define NI 10

typedef __attribute__((ext_vector_type(8))) short short8;
typedef __attribute__((ext_vector_type(4))) float f32x4;

__device__ __forceinline__ float bf2f(unsigned int bits16) {
  union { unsigned int u; float f; } v; v.u = bits16 << 16; return v.f;
}
__device__ __forceinline__ unsigned short f2bf(float f) {
  __hip_bfloat16 h = __float2bfloat16(f);
  return *reinterpret_cast<unsigned short*>(&h);
}

// ---- merged pack: blocks [0, NI*HH) transpose x; blocks [NI*HH, +144) pack weights.
__global__ __launch_bounds__(256) void pack_k(const float* __restrict__ x,
    const float* __restrict__ w1, const float* __restrict__ w2,
    unsigned short* __restrict__ xb, unsigned short* __restrict__ wb1,
    unsigned short* __restrict__ wb2) {
  __shared__ unsigned short tb[128*68];
  const int tid = threadIdx.x;
  const int bx = blockIdx.x;
  if (bx >= NI*HH) {            // ---- weight part
    int idx = (bx - NI*HH)*256 + tid;
    if (idx < 64*576) {
      int oc = idx / 576, rem = idx - oc*576, kk = rem >> 6, ic = rem & 63;
      wb1[idx] = f2bf(w1[(oc*64 + ic)*9 + kk]);
    }
    if (idx < 16*576) {
      int oc = idx / 576, rem = idx - oc*576, kk = rem >> 6, ic = rem & 63;
      wb2[idx] = (oc < 9) ? f2bf(w2[(oc*64 + ic)*9 + kk]) : (unsigned short)0;
    }
    return;
  }
  const int n = bx >> 7, h = bx & 127;
  const int bi = n / 5, ti = n - bi*5;
  const float* xp = x + ((size_t)bi*CC*TT + ti)*HW + (size_t)h*WW;
  for (int e = tid; e < 64*128; e += 256) {
    int ci = e >> 7, w = e & 127;
    tb[w*68 + ci] = f2bf(xp[(size_t)ci*TT*HW + w]);
  }
  __syncthreads();
  unsigned short* dst = xb + ((size_t)n*HW + (size_t)h*WW)*64;
  for (int e = tid; e < 2048; e += 256) {
    int w = e >> 4, c = e & 15;
    *(uint2*)(dst + w*64 + c*4) = *(const uint2*)(&tb[w*68 + c*4]);
  }
}

// ---- conv1 v4: 16x16 tile, 32 oc, 4 waves. Weights PRELOADED to registers
// (36 short8 = 144 VGPR) before staging, so their latency hides under the
// x-staging phase; post-barrier loop is pure ds_read+MFMA. (256,2) -> ~256 VGPR cap.
__global__ __launch_bounds__(256, 2) void conv1_mfma(
    const unsigned short* __restrict__ xb, const unsigned short* __restrict__ wb1,
    const float* __restrict__ b1, unsigned short* __restrict__ yb) {
  __shared__ unsigned short xt[324*64];    // 18x18 halo x 64 ic = 41472 B
  const int tid = threadIdx.x;
  const int wave = tid >> 6, lane = tid & 63, q = lane >> 4, r = lane & 15;
  const int n = blockIdx.z >> 1, ocg = (blockIdx.z & 1) << 5;
  const int h0 = blockIdx.y << 4, w0 = blockIdx.x << 4;
  const unsigned short* xn = xb + (size_t)n*HW*64;

  // ---- preload all weight fragments (independent loads, issued up front)
  short8 wr[9][2][2];
  {
    const unsigned short* wp0 = wb1 + (size_t)(ocg +      r)*576 + (q << 3);
    const unsigned short* wp1 = wb1 + (size_t)(ocg + 16 + r)*576 + (q << 3);
    #pragma unroll
    for (int kk = 0; kk < 9; ++kk)
      #pragma unroll
      for (int half = 0; half < 2; ++half) {
        wr[kk][half][0] = *(const short8*)(wp0 + kk*64 + half*32);
        wr[kk][half][1] = *(const short8*)(wp1 + kk*64 + half*32);
      }
  }

  // ---- stage x halo tile (overlaps with weight loads in flight)
  for (int e = tid; e < 2592; e += 256) {           // 324 sp x 8 chunks, 16B
    int sp = e >> 3, c = e & 7;
    int sr = sp / 18, sc = sp - sr*18;
    int gh = h0 + sr - 1, gw = w0 + sc - 1;
    uint4 v = make_uint4(0u,0u,0u,0u);
    if (gh >= 0 && gh < HH && gw >= 0 && gw < WW)
      v = *(const uint4*)(xn + ((size_t)(gh*WW + gw))*64 + (c << 3));
    *(uint4*)(&xt[sp*64 + ((c ^ (sp & 7)) << 3)]) = v;
  }
  __syncthreads();

  f32x4 zero4 = {0.f, 0.f, 0.f, 0.f};
  f32x4 acc[4][2];
  #pragma unroll
  for (int i = 0; i < 4; ++i)
    #pragma unroll
    for (int g = 0; g < 2; ++g) acc[i][g] = zero4;

  #pragma unroll
  for (int kk = 0; kk < 9; ++kk) {
    const int dy = kk / 3, dx = kk - dy*3;
    #pragma unroll
    for (int half = 0; half < 2; ++half) {
      #pragma unroll
      for (int i = 0; i < 4; ++i) {
        int sp = (wave*4 + i + dy)*18 + (r + dx);
        short8 b = *(const short8*)(&xt[sp*64 + ((((half << 2) | q) ^ (sp & 7)) << 3)]);
        acc[i][0] = __builtin_amdgcn_mfma_f32_16x16x32_bf16(wr[kk][half][0], b, acc[i][0], 0, 0, 0);
        acc[i][1] = __builtin_amdgcn_mfma_f32_16x16x32_bf16(wr[kk][half][1], b, acc[i][1], 0, 0, 0);
      }
    }
  }

  #pragma unroll
  for (int i = 0; i < 4; ++i) {
    int py = wave*4 + i;
    unsigned short* yp = yb + ((size_t)n*HW + (h0+py)*WW + (w0+r))*64;
    #pragma unroll
    for (int g = 0; g < 2; ++g) {
      int oc0 = ocg + g*16 + (q << 2);
      f32x4 bias = *(const f32x4*)(b1 + oc0);
      float v0 = acc[i][g][0] + bias[0]; v0 = (v0 >= 0.f) ? v0 : 0.2f*v0;
      float v1 = acc[i][g][1] + bias[1]; v1 = (v1 >= 0.f) ? v1 : 0.2f*v1;
      float v2 = acc[i][g][2] + bias[2]; v2 = (v2 >= 0.f) ? v2 : 0.2f*v2;
      float v3 = acc[i][g][3] + bias[3]; v3 = (v3 >= 0.f) ? v3 : 0.2f*v3;
      uint2 pk;
      pk.x = (unsigned int)f2bf(v0) | ((unsigned int)f2bf(v1) << 16);
      pk.y = (unsigned int)f2bf(v2) | ((unsigned int)f2bf(v3) << 16);
      *(uint2*)(yp + oc0) = pk;
    }
  }
}

// ---- conv2 v4: 16x8 tile, 16 oc (9 real), 4 waves, preloaded weights (18 short8).
__global__ __launch_bounds__(256, 3) void conv2_mfma(
    const unsigned short* __restrict__ yb, const unsigned short* __restrict__ wb2,
    const float* __restrict__ b2, float* __restrict__ ker0) {
  __shared__ unsigned short yt[180*64];    // 10x18 halo = 23040 B
  const int tid = threadIdx.x;
  const int wave = tid >> 6, lane = tid & 63, q = lane >> 4, r = lane & 15;
  const int n = blockIdx.z;
  const int h0 = blockIdx.y << 3, w0 = blockIdx.x << 4;
  const unsigned short* yn = yb + (size_t)n*HW*64;

  short8 wr[9][2];
  {
    const unsigned short* wp = wb2 + (size_t)r*576 + (q << 3);
    #pragma unroll
    for (int kk = 0; kk < 9; ++kk)
      #pragma unroll
      for (int half = 0; half < 2; ++half)
        wr[kk][half] = *(const short8*)(wp + kk*64 + half*32);
  }

  for (int e = tid; e < 1440; e += 256) {
    int sp = e >> 3, c = e & 7;
    int sr = sp / 18, sc = sp - sr*18;
    int gh = h0 + sr - 1, gw = w0 + sc - 1;
    uint4 v = make_uint4(0u,0u,0u,0u);
    if (gh >= 0 && gh < HH && gw >= 0 && gw < WW)
      v = *(const uint4*)(yn + ((size_t)(gh*WW + gw))*64 + (c << 3));
    *(uint4*)(&yt[sp*64 + ((c ^ (sp & 7)) << 3)]) = v;
  }
  __syncthreads();

  f32x4 zero4 = {0.f, 0.f, 0.f, 0.f};
  f32x4 acc[2];
  #pragma unroll
  for (int i = 0; i < 2; ++i) acc[i] = zero4;

  #pragma unroll
  for (int kk = 0; kk < 9; ++kk) {
    const int dy = kk / 3, dx = kk - dy*3;
    #pragma unroll
    for (int half = 0; half < 2; ++half) {
      #pragma unroll
      for (int i = 0; i < 2; ++i) {
        int sp = (wave*2 + i + dy)*18 + (r + dx);
        short8 b = *(const short8*)(&yt[sp*64 + ((((half << 2) | q) ^ (sp & 7)) << 3)]);
        acc[i] = __builtin_amdgcn_mfma_f32_16x16x32_bf16(wr[kk][half], b, acc[i], 0, 0, 0);
      }
    }
  }

  #pragma unroll
  for (int i = 0; i < 2; ++i) {
    int py = wave*2 + i;
    #pragma unroll
    for (int t2 = 0; t2 < 4; ++t2) {
      int oc = (q << 2) + t2;
      if (oc < 9)
        ker0[((size_t)n*9 + oc)*HW + (h0+py)*WW + w0 + r] = acc[i][t2] + b2[oc];
    }
  }
}

// ---- dynamic filtering: 16x16 tile x 4 ci per block, grid (8,8,32).
__global__ __launch_bounds__(256) void dynf_k(
    const unsigned short* __restrict__ xb, const float* __restrict__ ker0,
    float* __restrict__ out) {
  __shared__ float xs[TT*324*4];           // 25920 B
  const int tw = threadIdx.x, th = threadIdx.y;
  const int tid = th*16 + tw;
  const int wz = blockIdx.z;
  const int bi = wz >> 4, ci0 = (wz & 15) << 2;
  const int h0 = blockIdx.y << 4, w0 = blockIdx.x << 4;
  const int pix = (h0+th)*WW + w0 + tw;

  float kv[45]; float s = 0.f;
  #pragma unroll
  for (int t5 = 0; t5 < TT; ++t5)
    #pragma unroll
    for (int kk = 0; kk < 9; ++kk) {
      float v = ker0[((size_t)(bi*TT + t5)*9 + kk)*HW + pix];
      kv[t5*9 + kk] = v; s += v;
    }
  const float m = (s - 1.f) * (1.f/45.f);
  #pragma unroll
  for (int qq = 0; qq < 45; ++qq) kv[qq] -= m;

  for (int e = tid; e < TT*324; e += 256) {
    int t5 = e / 324, sp = e - t5*324;
    int rr = sp / 18, cc = sp - rr*18;
    int gh = min(max(h0 + rr - 1, 0), HH-1);
    int gw = min(max(w0 + cc - 1, 0), WW-1);
    uint2 raw = *(const uint2*)(xb + ((size_t)(bi*TT + t5)*HW + gh*WW + gw)*64 + ci0);
    f32x4 f;
    f[0] = bf2f(raw.x & 0xffffu);
    f[1] = bf2f(raw.x >> 16);
    f[2] = bf2f(raw.y & 0xffffu);
    f[3] = bf2f(raw.y >> 16);
    *(f32x4*)(&xs[e << 2]) = f;
  }
  __syncthreads();

  float a0 = 0.f, a1 = 0.f, a2 = 0.f, a3 = 0.f;
  #pragma unroll
  for (int t5 = 0; t5 < TT; ++t5)
    #pragma unroll
    for (int dy = 0; dy < 3; ++dy)
      #pragma unroll
      for (int dx = 0; dx < 3; ++dx) {
        f32x4 xv = *(const f32x4*)(&xs[(t5*324 + (th+dy)*18 + (tw+dx)) << 2]);
        float k = kv[t5*9 + dy*3 + dx];
        a0 = fmaf(xv[0], k, a0); a1 = fmaf(xv[1], k, a1);
        a2 = fmaf(xv[2], k, a2); a3 = fmaf(xv[3], k, a3);
      }
  float* op = out + ((size_t)(bi*CC + ci0))*HW + pix;
  op[0] = a0; op[HW] = a1; op[2*(size_t)HW] = a2; op[3*(size_t)HW] = a3;
}

extern "C" void kernel_launch(void* const* d_in, const int* in_sizes, int n_in,
                              void* d_out, int out_size, void* d_ws, size_t ws_size,
                              hipStream_t stream) {
  const float* x  = (const float*)d_in[0];
  const float* w1 = (const float*)d_in[1];
  const float* b1 = (const float*)d_in[2];
  const float* w2 = (const float*)d_in[3];
  const float* b2 = (const float*)d_in[4];
  float* out = (float*)d_out;

  unsigned short* xb  = (unsigned short*)d_ws;
  unsigned short* yb  = xb + (size_t)NI*HW*64;
  float*          ker0 = (float*)(yb + (size_t)NI*HW*64);
  unsigned short* wb1 = (unsigned short*)(ker0 + (size_t)NI*9*HW);
  unsigned short* wb2 = wb1 + 64*576;

  pack_k    <<<NI*HH + 144, 256, 0, stream>>>(x, w1, w2, xb, wb1, wb2);
  conv1_mfma<<<dim3(8,8,2*NI), 256, 0, stream>>>(xb, wb1, b1, yb);
  conv2_mfma<<<dim3(8,16,NI), 256, 0, stream>>>(yb, wb2, b2, ker0);
  dynf_k    <<<dim3(8,8,32), dim3(16,16), 0, stream>>>(xb, ker0, out);
}

// Round 7
// 156.492 us; speedup vs baseline: 1.1569x; 1.0915x over previous
//
#include <hip/hip_runtime.h>
#include <hip/hip_bf16.h>

#define HH 128
#define WW 128
#define CC 64
#define TT 5
#define HW (HH*WW)
#define NI 10

typedef __attribute__((ext_vector_type(8))) short short8;
typedef __attribute__((ext_vector_type(4))) float f32x4;

__device__ __forceinline__ float bf2f(unsigned int bits16) {
  union { unsigned int u; float f; } v; v.u = bits16 << 16; return v.f;
}
__device__ __forceinline__ unsigned short f2bf(float f) {
  __hip_bfloat16 h = __float2bfloat16(f);
  return *reinterpret_cast<unsigned short*>(&h);
}

// ---- merged pack: blocks [0, NI*HH) transpose x; blocks [NI*HH, +144) pack weights.
__global__ __launch_bounds__(256) void pack_k(const float* __restrict__ x,
    const float* __restrict__ w1, const float* __restrict__ w2,
    unsigned short* __restrict__ xb, unsigned short* __restrict__ wb1,
    unsigned short* __restrict__ wb2) {
  __shared__ unsigned short tb[128*68];
  const int tid = threadIdx.x;
  const int bx = blockIdx.x;
  if (bx >= NI*HH) {            // ---- weight part
    int idx = (bx - NI*HH)*256 + tid;
    if (idx < 64*576) {
      int oc = idx / 576, rem = idx - oc*576, kk = rem >> 6, ic = rem & 63;
      wb1[idx] = f2bf(w1[(oc*64 + ic)*9 + kk]);
    }
    if (idx < 16*576) {
      int oc = idx / 576, rem = idx - oc*576, kk = rem >> 6, ic = rem & 63;
      wb2[idx] = (oc < 9) ? f2bf(w2[(oc*64 + ic)*9 + kk]) : (unsigned short)0;
    }
    return;
  }
  const int n = bx >> 7, h = bx & 127;
  const int bi = n / 5, ti = n - bi*5;
  const float* xp = x + ((size_t)bi*CC*TT + ti)*HW + (size_t)h*WW;
  for (int e = tid; e < 64*128; e += 256) {
    int ci = e >> 7, w = e & 127;
    tb[w*68 + ci] = f2bf(xp[(size_t)ci*TT*HW + w]);
  }
  __syncthreads();
  unsigned short* dst = xb + ((size_t)n*HW + (size_t)h*WW)*64;
  for (int e = tid; e < 2048; e += 256) {
    int w = e >> 4, c = e & 15;
    *(uint2*)(dst + w*64 + c*4) = *(const uint2*)(&tb[w*68 + c*4]);
  }
}

// ---- conv1 v5: 16x16 tile, 32 oc, 4 waves. BOTH operands in LDS.
// Weights staged lane-major per MFMA fragment: wt[frag][lane] 16B each ->
// ds_read_b128 at base+lane*16, deterministically conflict-free. Inner loop
// has ZERO global accesses. LDS 41472+36864=78336 B -> 2 blocks/CU.
// grid (8,8,20): z = n*2 + ocg.
__global__ __launch_bounds__(256) void conv1_mfma(
    const unsigned short* __restrict__ xb, const unsigned short* __restrict__ wb1,
    const float* __restrict__ b1, unsigned short* __restrict__ yb) {
  __shared__ unsigned short xt[324*64];    // 18x18 halo x 64 ic = 41472 B
  __shared__ unsigned short wt[36*512];    // 36 frags x 64 lanes x 8 shorts = 36864 B
  const int tid = threadIdx.x;
  const int wave = tid >> 6, lane = tid & 63, q = lane >> 4, r = lane & 15;
  const int n = blockIdx.z >> 1, ocg = (blockIdx.z & 1) << 5;
  const int h0 = blockIdx.y << 4, w0 = blockIdx.x << 4;
  const unsigned short* xn = xb + (size_t)n*HW*64;

  // ---- stage weights in fragment order: frag = kk*4 + half*2 + g
  {
    const unsigned short* wsrc = wb1 + (size_t)ocg*576;
    for (int e = tid; e < 2304; e += 256) {
      int frag = e >> 6, ln = e & 63;
      int kk = frag >> 2, rem = frag & 3, half = rem >> 1, g = rem & 1;
      *(uint4*)(&wt[e << 3]) = *(const uint4*)(
          wsrc + (size_t)(g*16 + (ln & 15))*576 + kk*64 + half*32 + ((ln >> 4) << 3));
    }
  }
  // ---- stage x halo tile
  for (int e = tid; e < 2592; e += 256) {           // 324 sp x 8 chunks, 16B
    int sp = e >> 3, c = e & 7;
    int sr = sp / 18, sc = sp - sr*18;
    int gh = h0 + sr - 1, gw = w0 + sc - 1;
    uint4 v = make_uint4(0u,0u,0u,0u);
    if (gh >= 0 && gh < HH && gw >= 0 && gw < WW)
      v = *(const uint4*)(xn + ((size_t)(gh*WW + gw))*64 + (c << 3));
    *(uint4*)(&xt[sp*64 + ((c ^ (sp & 7)) << 3)]) = v;
  }
  __syncthreads();

  f32x4 zero4 = {0.f, 0.f, 0.f, 0.f};
  f32x4 acc[4][2];
  #pragma unroll
  for (int i = 0; i < 4; ++i)
    #pragma unroll
    for (int g = 0; g < 2; ++g) acc[i][g] = zero4;

  #pragma unroll
  for (int kk = 0; kk < 9; ++kk) {
    const int dy = kk / 3, dx = kk - dy*3;
    #pragma unroll
    for (int half = 0; half < 2; ++half) {
      short8 a0 = *(const short8*)(&wt[((kk*4 + half*2 + 0) << 9) + (lane << 3)]);
      short8 a1 = *(const short8*)(&wt[((kk*4 + half*2 + 1) << 9) + (lane << 3)]);
      #pragma unroll
      for (int i = 0; i < 4; ++i) {
        int sp = (wave*4 + i + dy)*18 + (r + dx);
        short8 b = *(const short8*)(&xt[sp*64 + ((((half << 2) | q) ^ (sp & 7)) << 3)]);
        acc[i][0] = __builtin_amdgcn_mfma_f32_16x16x32_bf16(a0, b, acc[i][0], 0, 0, 0);
        acc[i][1] = __builtin_amdgcn_mfma_f32_16x16x32_bf16(a1, b, acc[i][1], 0, 0, 0);
      }
    }
  }

  #pragma unroll
  for (int i = 0; i < 4; ++i) {
    int py = wave*4 + i;
    unsigned short* yp = yb + ((size_t)n*HW + (h0+py)*WW + (w0+r))*64;
    #pragma unroll
    for (int g = 0; g < 2; ++g) {
      int oc0 = ocg + g*16 + (q << 2);
      f32x4 bias = *(const f32x4*)(b1 + oc0);
      float v0 = acc[i][g][0] + bias[0]; v0 = (v0 >= 0.f) ? v0 : 0.2f*v0;
      float v1 = acc[i][g][1] + bias[1]; v1 = (v1 >= 0.f) ? v1 : 0.2f*v1;
      float v2 = acc[i][g][2] + bias[2]; v2 = (v2 >= 0.f) ? v2 : 0.2f*v2;
      float v3 = acc[i][g][3] + bias[3]; v3 = (v3 >= 0.f) ? v3 : 0.2f*v3;
      uint2 pk;
      pk.x = (unsigned int)f2bf(v0) | ((unsigned int)f2bf(v1) << 16);
      pk.y = (unsigned int)f2bf(v2) | ((unsigned int)f2bf(v3) << 16);
      *(uint2*)(yp + oc0) = pk;
    }
  }
}

// ---- conv2 v5: 16x8 tile, 16 oc (9 real), 4 waves, weights in LDS frag-order.
// LDS 23040 + 18432 = 41472 B -> 3 blocks/CU. grid (8,16,10).
__global__ __launch_bounds__(256) void conv2_mfma(
    const unsigned short* __restrict__ yb, const unsigned short* __restrict__ wb2,
    const float* __restrict__ b2, float* __restrict__ ker0) {
  __shared__ unsigned short yt[180*64];    // 10x18 halo = 23040 B
  __shared__ unsigned short wt[18*512];    // 18 frags = 18432 B
  const int tid = threadIdx.x;
  const int wave = tid >> 6, lane = tid & 63, q = lane >> 4, r = lane & 15;
  const int n = blockIdx.z;
  const int h0 = blockIdx.y << 3, w0 = blockIdx.x << 4;
  const unsigned short* yn = yb + (size_t)n*HW*64;

  // frag = kk*2 + half
  for (int e = tid; e < 1152; e += 256) {
    int frag = e >> 6, ln = e & 63;
    int kk = frag >> 1, half = frag & 1;
    *(uint4*)(&wt[e << 3]) = *(const uint4*)(
        wb2 + (size_t)(ln & 15)*576 + kk*64 + half*32 + ((ln >> 4) << 3));
  }
  for (int e = tid; e < 1440; e += 256) {
    int sp = e >> 3, c = e & 7;
    int sr = sp / 18, sc = sp - sr*18;
    int gh = h0 + sr - 1, gw = w0 + sc - 1;
    uint4 v = make_uint4(0u,0u,0u,0u);
    if (gh >= 0 && gh < HH && gw >= 0 && gw < WW)
      v = *(const uint4*)(yn + ((size_t)(gh*WW + gw))*64 + (c << 3));
    *(uint4*)(&yt[sp*64 + ((c ^ (sp & 7)) << 3)]) = v;
  }
  __syncthreads();

  f32x4 zero4 = {0.f, 0.f, 0.f, 0.f};
  f32x4 acc[2];
  #pragma unroll
  for (int i = 0; i < 2; ++i) acc[i] = zero4;

  #pragma unroll
  for (int kk = 0; kk < 9; ++kk) {
    const int dy = kk / 3, dx = kk - dy*3;
    #pragma unroll
    for (int half = 0; half < 2; ++half) {
      short8 a = *(const short8*)(&wt[((kk*2 + half) << 9) + (lane << 3)]);
      #pragma unroll
      for (int i = 0; i < 2; ++i) {
        int sp = (wave*2 + i + dy)*18 + (r + dx);
        short8 b = *(const short8*)(&yt[sp*64 + ((((half << 2) | q) ^ (sp & 7)) << 3)]);
        acc[i] = __builtin_amdgcn_mfma_f32_16x16x32_bf16(a, b, acc[i], 0, 0, 0);
      }
    }
  }

  #pragma unroll
  for (int i = 0; i < 2; ++i) {
    int py = wave*2 + i;
    #pragma unroll
    for (int t2 = 0; t2 < 4; ++t2) {
      int oc = (q << 2) + t2;
      if (oc < 9)
        ker0[((size_t)n*9 + oc)*HW + (h0+py)*WW + w0 + r] = acc[i][t2] + b2[oc];
    }
  }
}

// ---- dynamic filtering: 16x16 tile x 4 ci per block, grid (8,8,32).
__global__ __launch_bounds__(256) void dynf_k(
    const unsigned short* __restrict__ xb, const float* __restrict__ ker0,
    float* __restrict__ out) {
  __shared__ float xs[TT*324*4];           // 25920 B
  const int tw = threadIdx.x, th = threadIdx.y;
  const int tid = th*16 + tw;
  const int wz = blockIdx.z;
  const int bi = wz >> 4, ci0 = (wz & 15) << 2;
  const int h0 = blockIdx.y << 4, w0 = blockIdx.x << 4;
  const int pix = (h0+th)*WW + w0 + tw;

  float kv[45]; float s = 0.f;
  #pragma unroll
  for (int t5 = 0; t5 < TT; ++t5)
    #pragma unroll
    for (int kk = 0; kk < 9; ++kk) {
      float v = ker0[((size_t)(bi*TT + t5)*9 + kk)*HW + pix];
      kv[t5*9 + kk] = v; s += v;
    }
  const float m = (s - 1.f) * (1.f/45.f);
  #pragma unroll
  for (int qq = 0; qq < 45; ++qq) kv[qq] -= m;

  for (int e = tid; e < TT*324; e += 256) {
    int t5 = e / 324, sp = e - t5*324;
    int rr = sp / 18, cc = sp - rr*18;
    int gh = min(max(h0 + rr - 1, 0), HH-1);
    int gw = min(max(w0 + cc - 1, 0), WW-1);
    uint2 raw = *(const uint2*)(xb + ((size_t)(bi*TT + t5)*HW + gh*WW + gw)*64 + ci0);
    f32x4 f;
    f[0] = bf2f(raw.x & 0xffffu);
    f[1] = bf2f(raw.x >> 16);
    f[2] = bf2f(raw.y & 0xffffu);
    f[3] = bf2f(raw.y >> 16);
    *(f32x4*)(&xs[e << 2]) = f;
  }
  __syncthreads();

  float a0 = 0.f, a1 = 0.f, a2 = 0.f, a3 = 0.f;
  #pragma unroll
  for (int t5 = 0; t5 < TT; ++t5)
    #pragma unroll
    for (int dy = 0; dy < 3; ++dy)
      #pragma unroll
      for (int dx = 0; dx < 3; ++dx) {
        f32x4 xv = *(const f32x4*)(&xs[(t5*324 + (th+dy)*18 + (tw+dx)) << 2]);
        float k = kv[t5*9 + dy*3 + dx];
        a0 = fmaf(xv[0], k, a0); a1 = fmaf(xv[1], k, a1);
        a2 = fmaf(xv[2], k, a2); a3 = fmaf(xv[3], k, a3);
      }
  float* op = out + ((size_t)(bi*CC + ci0))*HW + pix;
  op[0] = a0; op[HW] = a1; op[2*(size_t)HW] = a2; op[3*(size_t)HW] = a3;
}

extern "C" void kernel_launch(void* const* d_in, const int* in_sizes, int n_in,
                              void* d_out, int out_size, void* d_ws, size_t ws_size,
                              hipStream_t stream) {
  const float* x  = (const float*)d_in[0];
  const float* w1 = (const float*)d_in[1];
  const float* b1 = (const float*)d_in[2];
  const float* w2 = (const float*)d_in[3];
  const float* b2 = (const float*)d_in[4];
  float* out = (float*)d_out;

  unsigned short* xb  = (unsigned short*)d_ws;
  unsigned short* yb  = xb + (size_t)NI*HW*64;
  float*          ker0 = (float*)(yb + (size_t)NI*HW*64);
  unsigned short* wb1 = (unsigned short*)(ker0 + (size_t)NI*9*HW);
  unsigned short* wb2 = wb1 + 64*576;

  pack_k    <<<NI*HH + 144, 256, 0, stream>>>(x, w1, w2, xb, wb1, wb2);
  conv1_mfma<<<dim3(8,8,2*NI), 256, 0, stream>>>(xb, wb1, b1, yb);
  conv2_mfma<<<dim3(8,16,NI), 256, 0, stream>>>(yb, wb2, b2, ker0);
  dynf_k    <<<dim3(8,8,32), dim3(16,16), 0, stream>>>(xb, ker0, out);
}

// Round 8
// 154.327 us; speedup vs baseline: 1.1731x; 1.0140x over previous
//
#include <hip/hip_runtime.h>
#include <hip/hip_bf16.h>

#define HH 128
#define WW 128
#define CC 64
#define TT 5
#define HW (HH*WW)
#define NI 10

typedef __attribute__((ext_vector_type(8))) short short8;
typedef __attribute__((ext_vector_type(4))) float f32x4;

__device__ __forceinline__ float bf2f(unsigned int bits16) {
  union { unsigned int u; float f; } v; v.u = bits16 << 16; return v.f;
}
__device__ __forceinline__ unsigned short f2bf(float f) {
  __hip_bfloat16 h = __float2bfloat16(f);
  return *reinterpret_cast<unsigned short*>(&h);
}

// ---- merged pack: blocks [0, NI*HH) transpose x; blocks [NI*HH, +144) pack weights.
__global__ __launch_bounds__(256) void pack_k(const float* __restrict__ x,
    const float* __restrict__ w1, const float* __restrict__ w2,
    unsigned short* __restrict__ xb, unsigned short* __restrict__ wb1,
    unsigned short* __restrict__ wb2) {
  __shared__ unsigned short tb[128*68];
  const int tid = threadIdx.x;
  const int bx = blockIdx.x;
  if (bx >= NI*HH) {            // ---- weight part
    int idx = (bx - NI*HH)*256 + tid;
    if (idx < 64*576) {
      int oc = idx / 576, rem = idx - oc*576, kk = rem >> 6, ic = rem & 63;
      wb1[idx] = f2bf(w1[(oc*64 + ic)*9 + kk]);
    }
    if (idx < 16*576) {
      int oc = idx / 576, rem = idx - oc*576, kk = rem >> 6, ic = rem & 63;
      wb2[idx] = (oc < 9) ? f2bf(w2[(oc*64 + ic)*9 + kk]) : (unsigned short)0;
    }
    return;
  }
  const int n = bx >> 7, h = bx & 127;
  const int bi = n / 5, ti = n - bi*5;
  const float* xp = x + ((size_t)bi*CC*TT + ti)*HW + (size_t)h*WW;
  for (int e = tid; e < 64*128; e += 256) {
    int ci = e >> 7, w = e & 127;
    tb[w*68 + ci] = f2bf(xp[(size_t)ci*TT*HW + w]);
  }
  __syncthreads();
  unsigned short* dst = xb + ((size_t)n*HW + (size_t)h*WW)*64;
  for (int e = tid; e < 2048; e += 256) {
    int w = e >> 4, c = e & 15;
    *(uint2*)(dst + w*64 + c*4) = *(const uint2*)(&tb[w*68 + c*4]);
  }
}

// ---- conv1 v6: v5 (both operands in LDS) + B-fragment reuse across rows.
// Per half: hold the 18 distinct B-frags (6 rows x 3 dx) in registers; the 9 kk
// MFMAs index into them. ds_read/wave: 108 -> 72. LDS 78336 B -> 2 blocks/CU.
// grid (8,8,20): z = n*2 + ocg.
__global__ __launch_bounds__(256, 2) void conv1_mfma(
    const unsigned short* __restrict__ xb, const unsigned short* __restrict__ wb1,
    const float* __restrict__ b1, unsigned short* __restrict__ yb) {
  __shared__ unsigned short xt[324*64];    // 18x18 halo x 64 ic = 41472 B
  __shared__ unsigned short wt[36*512];    // 36 frags x 64 lanes x 8 shorts = 36864 B
  const int tid = threadIdx.x;
  const int wave = tid >> 6, lane = tid & 63, q = lane >> 4, r = lane & 15;
  const int n = blockIdx.z >> 1, ocg = (blockIdx.z & 1) << 5;
  const int h0 = blockIdx.y << 4, w0 = blockIdx.x << 4;
  const unsigned short* xn = xb + (size_t)n*HW*64;

  // ---- stage weights in fragment order: frag = kk*4 + half*2 + g
  {
    const unsigned short* wsrc = wb1 + (size_t)ocg*576;
    for (int e = tid; e < 2304; e += 256) {
      int frag = e >> 6, ln = e & 63;
      int kk = frag >> 2, rem = frag & 3, half = rem >> 1, g = rem & 1;
      *(uint4*)(&wt[e << 3]) = *(const uint4*)(
          wsrc + (size_t)(g*16 + (ln & 15))*576 + kk*64 + half*32 + ((ln >> 4) << 3));
    }
  }
  // ---- stage x halo tile
  for (int e = tid; e < 2592; e += 256) {           // 324 sp x 8 chunks, 16B
    int sp = e >> 3, c = e & 7;
    int sr = sp / 18, sc = sp - sr*18;
    int gh = h0 + sr - 1, gw = w0 + sc - 1;
    uint4 v = make_uint4(0u,0u,0u,0u);
    if (gh >= 0 && gh < HH && gw >= 0 && gw < WW)
      v = *(const uint4*)(xn + ((size_t)(gh*WW + gw))*64 + (c << 3));
    *(uint4*)(&xt[sp*64 + ((c ^ (sp & 7)) << 3)]) = v;
  }
  __syncthreads();

  f32x4 zero4 = {0.f, 0.f, 0.f, 0.f};
  f32x4 acc[4][2];
  #pragma unroll
  for (int i = 0; i < 4; ++i)
    #pragma unroll
    for (int g = 0; g < 2; ++g) acc[i][g] = zero4;

  #pragma unroll
  for (int half = 0; half < 2; ++half) {
    // hold all 18 distinct B fragments for this half in registers
    short8 bf[6][3];
    #pragma unroll
    for (int rr = 0; rr < 6; ++rr)
      #pragma unroll
      for (int dx = 0; dx < 3; ++dx) {
        int sp = (wave*4 + rr)*18 + (r + dx);
        bf[rr][dx] = *(const short8*)(&xt[sp*64 + ((((half << 2) | q) ^ (sp & 7)) << 3)]);
      }
    #pragma unroll
    for (int kk = 0; kk < 9; ++kk) {
      const int dy = kk / 3, dx = kk - dy*3;
      short8 a0 = *(const short8*)(&wt[((kk*4 + half*2 + 0) << 9) + (lane << 3)]);
      short8 a1 = *(const short8*)(&wt[((kk*4 + half*2 + 1) << 9) + (lane << 3)]);
      #pragma unroll
      for (int i = 0; i < 4; ++i) {
        acc[i][0] = __builtin_amdgcn_mfma_f32_16x16x32_bf16(a0, bf[i+dy][dx], acc[i][0], 0, 0, 0);
        acc[i][1] = __builtin_amdgcn_mfma_f32_16x16x32_bf16(a1, bf[i+dy][dx], acc[i][1], 0, 0, 0);
      }
    }
  }

  #pragma unroll
  for (int i = 0; i < 4; ++i) {
    int py = wave*4 + i;
    unsigned short* yp = yb + ((size_t)n*HW + (h0+py)*WW + (w0+r))*64;
    #pragma unroll
    for (int g = 0; g < 2; ++g) {
      int oc0 = ocg + g*16 + (q << 2);
      f32x4 bias = *(const f32x4*)(b1 + oc0);
      float v0 = acc[i][g][0] + bias[0]; v0 = (v0 >= 0.f) ? v0 : 0.2f*v0;
      float v1 = acc[i][g][1] + bias[1]; v1 = (v1 >= 0.f) ? v1 : 0.2f*v1;
      float v2 = acc[i][g][2] + bias[2]; v2 = (v2 >= 0.f) ? v2 : 0.2f*v2;
      float v3 = acc[i][g][3] + bias[3]; v3 = (v3 >= 0.f) ? v3 : 0.2f*v3;
      uint2 pk;
      pk.x = (unsigned int)f2bf(v0) | ((unsigned int)f2bf(v1) << 16);
      pk.y = (unsigned int)f2bf(v2) | ((unsigned int)f2bf(v3) << 16);
      *(uint2*)(yp + oc0) = pk;
    }
  }
}

// ---- conv2 v6: weights in LDS + B-frag reuse (12 frags/half). 16x8 tile.
// LDS 23040 + 18432 = 41472 B -> 3 blocks/CU. grid (8,16,10).
__global__ __launch_bounds__(256) void conv2_mfma(
    const unsigned short* __restrict__ yb, const unsigned short* __restrict__ wb2,
    const float* __restrict__ b2, float* __restrict__ ker0) {
  __shared__ unsigned short yt[180*64];    // 10x18 halo = 23040 B
  __shared__ unsigned short wt[18*512];    // 18 frags = 18432 B
  const int tid = threadIdx.x;
  const int wave = tid >> 6, lane = tid & 63, q = lane >> 4, r = lane & 15;
  const int n = blockIdx.z;
  const int h0 = blockIdx.y << 3, w0 = blockIdx.x << 4;
  const unsigned short* yn = yb + (size_t)n*HW*64;

  // frag = kk*2 + half
  for (int e = tid; e < 1152; e += 256) {
    int frag = e >> 6, ln = e & 63;
    int kk = frag >> 1, half = frag & 1;
    *(uint4*)(&wt[e << 3]) = *(const uint4*)(
        wb2 + (size_t)(ln & 15)*576 + kk*64 + half*32 + ((ln >> 4) << 3));
  }
  for (int e = tid; e < 1440; e += 256) {
    int sp = e >> 3, c = e & 7;
    int sr = sp / 18, sc = sp - sr*18;
    int gh = h0 + sr - 1, gw = w0 + sc - 1;
    uint4 v = make_uint4(0u,0u,0u,0u);
    if (gh >= 0 && gh < HH && gw >= 0 && gw < WW)
      v = *(const uint4*)(yn + ((size_t)(gh*WW + gw))*64 + (c << 3));
    *(uint4*)(&yt[sp*64 + ((c ^ (sp & 7)) << 3)]) = v;
  }
  __syncthreads();

  f32x4 zero4 = {0.f, 0.f, 0.f, 0.f};
  f32x4 acc[2];
  #pragma unroll
  for (int i = 0; i < 2; ++i) acc[i] = zero4;

  #pragma unroll
  for (int half = 0; half < 2; ++half) {
    short8 bf[4][3];
    #pragma unroll
    for (int rr = 0; rr < 4; ++rr)
      #pragma unroll
      for (int dx = 0; dx < 3; ++dx) {
        int sp = (wave*2 + rr)*18 + (r + dx);
        bf[rr][dx] = *(const short8*)(&yt[sp*64 + ((((half << 2) | q) ^ (sp & 7)) << 3)]);
      }
    #pragma unroll
    for (int kk = 0; kk < 9; ++kk) {
      const int dy = kk / 3, dx = kk - dy*3;
      short8 a = *(const short8*)(&wt[((kk*2 + half) << 9) + (lane << 3)]);
      #pragma unroll
      for (int i = 0; i < 2; ++i)
        acc[i] = __builtin_amdgcn_mfma_f32_16x16x32_bf16(a, bf[i+dy][dx], acc[i], 0, 0, 0);
    }
  }

  #pragma unroll
  for (int i = 0; i < 2; ++i) {
    int py = wave*2 + i;
    #pragma unroll
    for (int t2 = 0; t2 < 4; ++t2) {
      int oc = (q << 2) + t2;
      if (oc < 9)
        ker0[((size_t)n*9 + oc)*HW + (h0+py)*WW + w0 + r] = acc[i][t2] + b2[oc];
    }
  }
}

// ---- dynamic filtering: 16x16 tile x 4 ci per block, grid (8,8,32).
__global__ __launch_bounds__(256) void dynf_k(
    const unsigned short* __restrict__ xb, const float* __restrict__ ker0,
    float* __restrict__ out) {
  __shared__ float xs[TT*324*4];           // 25920 B
  const int tw = threadIdx.x, th = threadIdx.y;
  const int tid = th*16 + tw;
  const int wz = blockIdx.z;
  const int bi = wz >> 4, ci0 = (wz & 15) << 2;
  const int h0 = blockIdx.y << 4, w0 = blockIdx.x << 4;
  const int pix = (h0+th)*WW + w0 + tw;

  float kv[45]; float s = 0.f;
  #pragma unroll
  for (int t5 = 0; t5 < TT; ++t5)
    #pragma unroll
    for (int kk = 0; kk < 9; ++kk) {
      float v = ker0[((size_t)(bi*TT + t5)*9 + kk)*HW + pix];
      kv[t5*9 + kk] = v; s += v;
    }
  const float m = (s - 1.f) * (1.f/45.f);
  #pragma unroll
  for (int qq = 0; qq < 45; ++qq) kv[qq] -= m;

  for (int e = tid; e < TT*324; e += 256) {
    int t5 = e / 324, sp = e - t5*324;
    int rr = sp / 18, cc = sp - rr*18;
    int gh = min(max(h0 + rr - 1, 0), HH-1);
    int gw = min(max(w0 + cc - 1, 0), WW-1);
    uint2 raw = *(const uint2*)(xb + ((size_t)(bi*TT + t5)*HW + gh*WW + gw)*64 + ci0);
    f32x4 f;
    f[0] = bf2f(raw.x & 0xffffu);
    f[1] = bf2f(raw.x >> 16);
    f[2] = bf2f(raw.y & 0xffffu);
    f[3] = bf2f(raw.y >> 16);
    *(f32x4*)(&xs[e << 2]) = f;
  }
  __syncthreads();

  float a0 = 0.f, a1 = 0.f, a2 = 0.f, a3 = 0.f;
  #pragma unroll
  for (int t5 = 0; t5 < TT; ++t5)
    #pragma unroll
    for (int dy = 0; dy < 3; ++dy)
      #pragma unroll
      for (int dx = 0; dx < 3; ++dx) {
        f32x4 xv = *(const f32x4*)(&xs[(t5*324 + (th+dy)*18 + (tw+dx)) << 2]);
        float k = kv[t5*9 + dy*3 + dx];
        a0 = fmaf(xv[0], k, a0); a1 = fmaf(xv[1], k, a1);
        a2 = fmaf(xv[2], k, a2); a3 = fmaf(xv[3], k, a3);
      }
  float* op = out + ((size_t)(bi*CC + ci0))*HW + pix;
  op[0] = a0; op[HW] = a1; op[2*(size_t)HW] = a2; op[3*(size_t)HW] = a3;
}

extern "C" void kernel_launch(void* const* d_in, const int* in_sizes, int n_in,
                              void* d_out, int out_size, void* d_ws, size_t ws_size,
                              hipStream_t stream) {
  const float* x  = (const float*)d_in[0];
  const float* w1 = (const float*)d_in[1];
  const float* b1 = (const float*)d_in[2];
  const float* w2 = (const float*)d_in[3];
  const float* b2 = (const float*)d_in[4];
  float* out = (float*)d_out;

  unsigned short* xb  = (unsigned short*)d_ws;
  unsigned short* yb  = xb + (size_t)NI*HW*64;
  float*          ker0 = (float*)(yb + (size_t)NI*HW*64);
  unsigned short* wb1 = (unsigned short*)(ker0 + (size_t)NI*9*HW);
  unsigned short* wb2 = wb1 + 64*576;

  pack_k    <<<NI*HH + 144, 256, 0, stream>>>(x, w1, w2, xb, wb1, wb2);
  conv1_mfma<<<dim3(8,8,2*NI), 256, 0, stream>>>(xb, wb1, b1, yb);
  conv2_mfma<<<dim3(8,16,NI), 256, 0, stream>>>(yb, wb2, b2, ker0);
  dynf_k    <<<dim3(8,8,32), dim3(16,16), 0, stream>>>(xb, ker0, out);
}